// Round 13
// baseline (246.585 us; speedup 1.0000x reference)
//
#include <hip/hip_runtime.h>
#include <hip/hip_bf16.h>
#include <math.h>

#define NEG_SLOPE 0.2f
#define EPSBN 1e-5f
#define NREP 8

typedef __attribute__((ext_vector_type(8))) short bf16x8;
typedef __attribute__((ext_vector_type(4))) float f32x4;

__device__ __forceinline__ float bfu2f(unsigned u_lo16) { return __uint_as_float(u_lo16 << 16); }
__device__ __forceinline__ unsigned short f2bf(float f) {
    return __bfloat16_as_ushort(__float2bfloat16(f));
}
__device__ __forceinline__ void splitf(float v, unsigned short &h, unsigned short &l) {
    __hip_bfloat16 hb = __float2bfloat16(v);
    float r = v - __bfloat162float(hb);
    h = __bfloat16_as_ushort(hb);
    l = __bfloat16_as_ushort(__float2bfloat16(r));
}

// ---------------- precompute v = W1 @ a vectors (2 blocks x 256) -------------
__global__ __launch_bounds__(256) void precompute_v(
    const float* __restrict__ W1, const float* __restrict__ as1,
    const float* __restrict__ ad1, float* __restrict__ vsd)
{
    int idx = blockIdx.x * 256 + threadIdx.x;
    if (idx >= 512) return;
    int k = idx & 127, which = idx >> 7;
    const float* av = ((which >= 2) ? ad1 : as1) + ((which & 1) ? 128 : 0);
    const float* wr = W1 + (size_t)k * 256 + ((which & 1) ? 128 : 0);
    float v = 0.f;
    for (int c = 0; c < 128; ++c) v += wr[c] * av[c];
    vsd[which * 128 + k] = v;
}

// ---------------- mega-prep: count_edges(8-rep) | split_x+attn | split_w -----
__global__ __launch_bounds__(256) void prep(
    const float* __restrict__ X, const float* __restrict__ vsd,
    const float* __restrict__ W1, const float* __restrict__ W2,
    const int* __restrict__ ei,
    unsigned short* __restrict__ Xh, float* __restrict__ asrc, float* __restrict__ adst,
    unsigned short* __restrict__ w1th, unsigned short* __restrict__ w1tl,
    unsigned short* __restrict__ w2th, unsigned short* __restrict__ w2tl,
    int* __restrict__ counts, int* __restrict__ erank,
    int Nn, int E, int nwB, int countB)
{
    const int b = blockIdx.x;
    const int tid = threadIdx.x;
    if (b < countB) {
        // ---- count_edges: replica r = e&7
        int e = b * 256 + tid;
        int E2 = E + Nn;
        if (e >= E2) return;
        int dst = (e < E) ? ei[E + e] : (e - E);
        erank[e] = atomicAdd(&counts[(e & (NREP - 1)) * Nn + dst], 1);
    } else if (b < countB + nwB) {
        // ---- split x -> bf16 plane + layer-1 attn coefficients
        int n = (int)(((b - countB) * 256 + tid) >> 6);
        int lane = tid & 63;
        if (n >= Nn) return;
        float2 xv = *(const float2*)(X + (size_t)n * 128 + lane * 2);
        unsigned short hh[2] = {f2bf(xv.x), f2bf(xv.y)};
        *(unsigned*)(Xh + (size_t)n * 128 + lane * 2) = *(unsigned*)hh;
        int k = lane * 2;
        float p0 = xv.x * vsd[k]       + xv.y * vsd[k + 1];
        float p1 = xv.x * vsd[128 + k] + xv.y * vsd[129 + k];
        float p2 = xv.x * vsd[256 + k] + xv.y * vsd[257 + k];
        float p3 = xv.x * vsd[384 + k] + xv.y * vsd[385 + k];
        for (int off = 32; off; off >>= 1) {
            p0 += __shfl_xor(p0, off); p1 += __shfl_xor(p1, off);
            p2 += __shfl_xor(p2, off); p3 += __shfl_xor(p3, off);
        }
        if (lane == 0) {
            asrc[n * 2] = p0; asrc[n * 2 + 1] = p1;
            adst[n * 2] = p2; adst[n * 2 + 1] = p3;
        }
    } else {
        // ---- split weights -> transposed split planes
        int idx = (b - countB - nwB) * 256 + tid;
        if (idx < 32768) {                      // W1 [128,256] -> [256,128]
            int nn = idx >> 7, k = idx & 127;
            unsigned short h, l; splitf(W1[(size_t)k * 256 + nn], h, l);
            w1th[idx] = h; w1tl[idx] = l;
        } else if (idx < 65536) {               // W2 [256,128] -> [128,256]
            int j = idx - 32768;
            int nn = j >> 8, k = j & 255;
            unsigned short h, l; splitf(W2[(size_t)k * 128 + nn], h, l);
            w2th[j] = h; w2tl[j] = l;
        }
    }
}

// ---------------- CSR scan (folds 8 replicas -> per-replica run in place) ----
__global__ __launch_bounds__(256) void scan_block(
    int* __restrict__ counts, int* __restrict__ offs, int* __restrict__ bsum, int Nn)
{
    __shared__ int s[256];
    int i = blockIdx.x * 256 + threadIdx.x;
    int v = 0;
    if (i < Nn) {
        int c[NREP];
#pragma unroll
        for (int r = 0; r < NREP; ++r) c[r] = counts[r * Nn + i];
        int run = 0;
#pragma unroll
        for (int r = 0; r < NREP; ++r) { counts[r * Nn + i] = run; run += c[r]; }
        v = run;
    }
    s[threadIdx.x] = v;
    __syncthreads();
    for (int off = 1; off < 256; off <<= 1) {
        int t = (threadIdx.x >= off) ? s[threadIdx.x - off] : 0;
        __syncthreads();
        s[threadIdx.x] += t;
        __syncthreads();
    }
    if (i < Nn) offs[i] = s[threadIdx.x] - v;
    if (threadIdx.x == 255) bsum[blockIdx.x] = s[255];
}

// fused scan_tops + add_offsets + offrep fusion:
// counts[r][i] becomes the ABSOLUTE base offs[i]+repoff[r][i] (single random
// read in fill_edges instead of two)
__global__ __launch_bounds__(256) void finalize_offsets(
    const int* __restrict__ bsum, int* __restrict__ offs,
    int* __restrict__ reps, int Nn, int E2)
{
    __shared__ int ws[4];
    int b = blockIdx.x, t = threadIdx.x;
    int v = (t < b) ? bsum[t] : 0;
    for (int off = 32; off; off >>= 1) v += __shfl_xor(v, off);
    if ((t & 63) == 0) ws[t >> 6] = v;
    __syncthreads();
    int S = ws[0] + ws[1] + ws[2] + ws[3];
    int i = b * 256 + t;
    if (i < Nn) {
        int o = offs[i] + S;
        offs[i] = o;
#pragma unroll
        for (int r = 0; r < NREP; ++r) reps[r * Nn + i] += o;
    }
    if (b == 0 && t == 0) offs[Nn] = E2;
}

// atomic-free scatter: ONE random read (offrep) + coalesced erank + scatter
__global__ void fill_edges(
    const int* __restrict__ ei, int E, int Nn,
    const int* __restrict__ offrep, const int* __restrict__ erank,
    int* __restrict__ esrc)
{
    int e = blockIdx.x * blockDim.x + threadIdx.x;
    int E2 = E + Nn;
    if (e >= E2) return;
    int src, dst;
    if (e < E) { src = ei[e]; dst = ei[E + e]; }
    else       { src = e - E; dst = e - E; }
    esrc[offrep[(e & (NREP - 1)) * Nn + dst] + erank[e]] = src;
}

// ---------------- unpack-FMA helpers ----------------------------------------
__device__ __forceinline__ void fma8(float wA, uint4 hv, float acc[8])
{
    acc[0] = fmaf(wA, bfu2f(hv.x & 0xffff), acc[0]);
    acc[1] = fmaf(wA, __uint_as_float(hv.x & 0xffff0000u), acc[1]);
    acc[2] = fmaf(wA, bfu2f(hv.y & 0xffff), acc[2]);
    acc[3] = fmaf(wA, __uint_as_float(hv.y & 0xffff0000u), acc[3]);
    acc[4] = fmaf(wA, bfu2f(hv.z & 0xffff), acc[4]);
    acc[5] = fmaf(wA, __uint_as_float(hv.z & 0xffff0000u), acc[5]);
    acc[6] = fmaf(wA, bfu2f(hv.w & 0xffff), acc[6]);
    acc[7] = fmaf(wA, __uint_as_float(hv.w & 0xffff0000u), acc[7]);
}

__device__ __forceinline__ void fma8x2(float wa, float wb, uint4 hv,
                                       float a0[8], float a1[8])
{
    float f;
    f = bfu2f(hv.x & 0xffff);                 a0[0]=fmaf(wa,f,a0[0]); a1[0]=fmaf(wb,f,a1[0]);
    f = __uint_as_float(hv.x & 0xffff0000u);  a0[1]=fmaf(wa,f,a0[1]); a1[1]=fmaf(wb,f,a1[1]);
    f = bfu2f(hv.y & 0xffff);                 a0[2]=fmaf(wa,f,a0[2]); a1[2]=fmaf(wb,f,a1[2]);
    f = __uint_as_float(hv.y & 0xffff0000u);  a0[3]=fmaf(wa,f,a0[3]); a1[3]=fmaf(wb,f,a1[3]);
    f = bfu2f(hv.z & 0xffff);                 a0[4]=fmaf(wa,f,a0[4]); a1[4]=fmaf(wb,f,a1[4]);
    f = __uint_as_float(hv.z & 0xffff0000u);  a0[5]=fmaf(wa,f,a0[5]); a1[5]=fmaf(wb,f,a1[5]);
    f = bfu2f(hv.w & 0xffff);                 a0[6]=fmaf(wa,f,a0[6]); a1[6]=fmaf(wb,f,a1[6]);
    f = __uint_as_float(hv.w & 0xffff0000u);  a0[7]=fmaf(wa,f,a0[7]); a1[7]=fmaf(wb,f,a1[7]);
}

// 1-head gather: 16 lanes/edge, 4 subslots, row 256 B
__device__ __forceinline__ void gather1h(
    int sj, float w, int nc, int sub,
    const char* __restrict__ hb_c, float acc[8])
{
    for (int t = 0; t < nc; t += 4) {
        int e = t + sub;
        int sA = __shfl(sj, e);
        float wA = __shfl(w, e);
        uint4 hv = *(const uint4*)(hb_c + sA * 256);
        fma8(wA, hv, acc);
    }
}

// dual-head x-gather: 16 lanes/edge, 4 subslots, row 256 B
__device__ __forceinline__ void gatherx(
    int sj, float w0, float w1, int nc, int sub,
    const char* __restrict__ hb_c, float a0[8], float a1[8])
{
    for (int t = 0; t < nc; t += 4) {
        int e = t + sub;
        int sA = __shfl(sj, e);
        float wa = __shfl(w0, e);
        float wb = __shfl(w1, e);
        uint4 hv = *(const uint4*)(hb_c + sA * 256);
        fma8x2(wa, wb, hv, a0, a1);
    }
}

// ---------------- SpMM on input features x (layer 1), dual-head -------------
__global__ __launch_bounds__(256) void spmm_x(
    const unsigned short* __restrict__ xh, const float* __restrict__ asrc,
    const float* __restrict__ adst, const int* __restrict__ offs,
    const int* __restrict__ esrc,
    unsigned short* __restrict__ xth, int Nn)
{
    int d = (int)((blockIdx.x * blockDim.x + threadIdx.x) >> 6);
    int lane = threadIdx.x & 63;
    if (d >= Nn) return;
    int beg = offs[d], end = offs[d + 1];
    int deg = end - beg;
    float ad0 = adst[d * 2], ad1 = adst[d * 2 + 1];
    const int sub = lane >> 4;
    const int cgrp = lane & 15;
    const char* hb_c = (const char*)xh + cgrp * 16;
    float a0[8] = {}, a1[8] = {};

    if (deg <= 64) {
        int sj = 0; float e0 = -1e30f, e1 = -1e30f;
        if (lane < deg) {
            sj = esrc[beg + lane];
            float2 av = *(const float2*)(asrc + (size_t)sj * 2);
            e0 = av.x + ad0; e0 = e0 > 0.f ? e0 : NEG_SLOPE * e0;
            e1 = av.y + ad1; e1 = e1 > 0.f ? e1 : NEG_SLOPE * e1;
        }
        float m0 = e0, m1 = e1;
        for (int off = 32; off; off >>= 1) {
            m0 = fmaxf(m0, __shfl_xor(m0, off));
            m1 = fmaxf(m1, __shfl_xor(m1, off));
        }
        float p0 = (lane < deg) ? expf(e0 - m0) : 0.f;
        float p1 = (lane < deg) ? expf(e1 - m1) : 0.f;
        float s0 = p0, s1 = p1;
        for (int off = 32; off; off >>= 1) {
            s0 += __shfl_xor(s0, off);
            s1 += __shfl_xor(s1, off);
        }
        float w0 = p0 * (1.f / s0), w1 = p1 * (1.f / s1);
        gatherx(sj, w0, w1, deg, sub, hb_c, a0, a1);
    } else {
        float m0 = -1e30f, m1 = -1e30f;
        for (int j = beg + lane; j < end; j += 64) {
            int s = esrc[j];
            float2 av = *(const float2*)(asrc + (size_t)s * 2);
            float e0 = av.x + ad0; e0 = e0 > 0.f ? e0 : NEG_SLOPE * e0;
            float e1 = av.y + ad1; e1 = e1 > 0.f ? e1 : NEG_SLOPE * e1;
            m0 = fmaxf(m0, e0); m1 = fmaxf(m1, e1);
        }
        for (int off = 32; off; off >>= 1) {
            m0 = fmaxf(m0, __shfl_xor(m0, off));
            m1 = fmaxf(m1, __shfl_xor(m1, off));
        }
        float s0 = 0.f, s1 = 0.f;
        for (int j = beg + lane; j < end; j += 64) {
            int s = esrc[j];
            float2 av = *(const float2*)(asrc + (size_t)s * 2);
            float e0 = av.x + ad0; e0 = e0 > 0.f ? e0 : NEG_SLOPE * e0;
            float e1 = av.y + ad1; e1 = e1 > 0.f ? e1 : NEG_SLOPE * e1;
            s0 += expf(e0 - m0); s1 += expf(e1 - m1);
        }
        for (int off = 32; off; off >>= 1) {
            s0 += __shfl_xor(s0, off);
            s1 += __shfl_xor(s1, off);
        }
        float rd0 = 1.f / s0, rd1 = 1.f / s1;
        for (int base = beg; base < end; base += 64) {
            int nc = end - base; if (nc > 64) nc = 64;
            int sj = 0; float w0 = 0.f, w1 = 0.f;
            if (lane < nc) {
                sj = esrc[base + lane];
                float2 av = *(const float2*)(asrc + (size_t)sj * 2);
                float e0 = av.x + ad0; e0 = e0 > 0.f ? e0 : NEG_SLOPE * e0;
                float e1 = av.y + ad1; e1 = e1 > 0.f ? e1 : NEG_SLOPE * e1;
                w0 = expf(e0 - m0) * rd0;
                w1 = expf(e1 - m1) * rd1;
            }
            gatherx(sj, w0, w1, nc, sub, hb_c, a0, a1);
        }
    }
#pragma unroll
    for (int i = 0; i < 8; ++i) {
        a0[i] += __shfl_xor(a0[i], 32); a0[i] += __shfl_xor(a0[i], 16);
        a1[i] += __shfl_xor(a1[i], 32); a1[i] += __shfl_xor(a1[i], 16);
    }
    if (lane < 16) {
        int cl = cgrp * 8;
        unsigned short h0[8], h1[8];
#pragma unroll
        for (int i = 0; i < 8; ++i) { h0[i] = f2bf(a0[i]); h1[i] = f2bf(a1[i]); }
        size_t rb = (size_t)d * 256;
        *(uint4*)(xth + rb + cl)       = *(uint4*)&h0[0];
        *(uint4*)(xth + rb + 128 + cl) = *(uint4*)&h1[0];
    }
}

// ---------------- GEMM1b: x~ @ W1 (block-diag per head) + BN + bf16 out -----
__global__ __launch_bounds__(256) void gemm_bn_split(
    const unsigned short* __restrict__ Ah,
    const unsigned short* __restrict__ Bth, const unsigned short* __restrict__ Btl,
    const float* __restrict__ bias, const float* __restrict__ gamma,
    const float* __restrict__ beta, const float* __restrict__ rm,
    const float* __restrict__ rv,
    unsigned short* __restrict__ Ch, int M)
{
    __shared__ unsigned short smem[3][128][32];
    const int tid = threadIdx.x;
    const int lane = tid & 63;
    const int wave = tid >> 6;
    const int fr = lane & 15, g = lane >> 4;
    const int wr = (wave >> 1) * 64, wc = (wave & 1) * 64;
    const int rowBase = blockIdx.x * 128, colBase = blockIdx.y * 128;

    f32x4 acc[4][4] = {};

    for (int kk = 0; kk < 128; kk += 32) {
#pragma unroll
        for (int i = 0; i < 2; ++i) {
            int idx = tid + 256 * i;
            int r = idx >> 2, c = (idx & 3) * 8;
            int grow = rowBase + r;
            uint4 va_h = make_uint4(0, 0, 0, 0);
            if (grow < M) va_h = *(const uint4*)(Ah + (size_t)grow * 256 + colBase + kk + c);
            *(uint4*)&smem[0][r][c] = va_h;
            int gcol = colBase + r;
            *(uint4*)&smem[1][r][c] = *(const uint4*)(Bth + (size_t)gcol * 128 + kk + c);
            *(uint4*)&smem[2][r][c] = *(const uint4*)(Btl + (size_t)gcol * 128 + kk + c);
        }
        __syncthreads();

        bf16x8 ah[4], bh[4], bl[4];
#pragma unroll
        for (int m = 0; m < 4; ++m)
            ah[m] = *(const bf16x8*)&smem[0][wr + m * 16 + fr][g * 8];
#pragma unroll
        for (int n = 0; n < 4; ++n) {
            bh[n] = *(const bf16x8*)&smem[1][wc + n * 16 + fr][g * 8];
            bl[n] = *(const bf16x8*)&smem[2][wc + n * 16 + fr][g * 8];
        }
#pragma unroll
        for (int m = 0; m < 4; ++m)
#pragma unroll
            for (int n = 0; n < 4; ++n) {
                acc[m][n] = __builtin_amdgcn_mfma_f32_16x16x32_bf16(ah[m], bh[n], acc[m][n], 0, 0, 0);
                acc[m][n] = __builtin_amdgcn_mfma_f32_16x16x32_bf16(ah[m], bl[n], acc[m][n], 0, 0, 0);
            }
        __syncthreads();
    }

    // bias + BN + ReLU
    {
        float bi[4], ga[4], bb[4], mu[4], iv[4];
#pragma unroll
        for (int n = 0; n < 4; ++n) {
            int c = colBase + wc + n * 16 + fr;
            bi[n] = bias[c]; ga[n] = gamma[c]; bb[n] = beta[c];
            mu[n] = rm[c];   iv[n] = rsqrtf(rv[c] + EPSBN);
        }
#pragma unroll
        for (int m = 0; m < 4; ++m)
#pragma unroll
            for (int n = 0; n < 4; ++n)
#pragma unroll
                for (int j = 0; j < 4; ++j) {
                    float v = acc[m][n][j] + bi[n];
                    v = ga[n] * (v - mu[n]) * iv[n] + bb[n];
                    acc[m][n][j] = fmaxf(v, 0.f);
                }
    }

    // transpose epilogue, bf16 stores
    float* Cs = (float*)&smem[0][0][0];
    const int rl_w = (wr >> 6) * 16;
#pragma unroll
    for (int m = 0; m < 4; ++m) {
        __syncthreads();
#pragma unroll
        for (int n = 0; n < 4; ++n)
#pragma unroll
            for (int j = 0; j < 4; ++j)
                Cs[(rl_w + g * 4 + j) * 132 + wc + n * 16 + fr] = acc[m][n][j];
        __syncthreads();
        int rl = tid >> 3, c16 = (tid & 7) * 16;
        int grow = rowBase + (rl >> 4) * 64 + m * 16 + (rl & 15);
        if (grow < M) {
            unsigned short th[16];
#pragma unroll
            for (int i = 0; i < 16; ++i) th[i] = f2bf(Cs[rl * 132 + c16 + i]);
            size_t ob = (size_t)grow * 256 + colBase + c16;
            *(uint4*)(Ch + ob)     = *(uint4*)&th[0];
            *(uint4*)(Ch + ob + 8) = *(uint4*)&th[8];
        }
    }
}

// ---------------- layer-2 GEMM (single A plane) + fused attn coefs ----------
__global__ __launch_bounds__(256) void gemm_bf16_attn(
    const unsigned short* __restrict__ Ah,
    const unsigned short* __restrict__ Bth, const unsigned short* __restrict__ Btl,
    unsigned short* __restrict__ Cb,
    const float* __restrict__ aSrc, const float* __restrict__ aDst,
    float* __restrict__ asrcOut, float* __restrict__ adstOut, int M)
{
    __shared__ unsigned short smem[3][128][32];
    const int tid = threadIdx.x;
    const int lane = tid & 63;
    const int wave = tid >> 6;
    const int fr = lane & 15, g = lane >> 4;
    const int wr = (wave >> 1) * 64, wc = (wave & 1) * 64;
    const int rowBase = blockIdx.x * 128;

    f32x4 acc[4][4] = {};

    for (int kk = 0; kk < 256; kk += 32) {
#pragma unroll
        for (int i = 0; i < 2; ++i) {
            int idx = tid + 256 * i;
            int r = idx >> 2, c = (idx & 3) * 8;
            int grow = rowBase + r;
            uint4 va_h = make_uint4(0, 0, 0, 0);
            if (grow < M) va_h = *(const uint4*)(Ah + (size_t)grow * 256 + kk + c);
            *(uint4*)&smem[0][r][c] = va_h;
            *(uint4*)&smem[1][r][c] = *(const uint4*)(Bth + (size_t)r * 256 + kk + c);
            *(uint4*)&smem[2][r][c] = *(const uint4*)(Btl + (size_t)r * 256 + kk + c);
        }
        __syncthreads();

        bf16x8 ah[4], bh[4], bl[4];
#pragma unroll
        for (int m = 0; m < 4; ++m)
            ah[m] = *(const bf16x8*)&smem[0][wr + m * 16 + fr][g * 8];
#pragma unroll
        for (int n = 0; n < 4; ++n) {
            bh[n] = *(const bf16x8*)&smem[1][wc + n * 16 + fr][g * 8];
            bl[n] = *(const bf16x8*)&smem[2][wc + n * 16 + fr][g * 8];
        }
#pragma unroll
        for (int m = 0; m < 4; ++m)
#pragma unroll
            for (int n = 0; n < 4; ++n) {
                acc[m][n] = __builtin_amdgcn_mfma_f32_16x16x32_bf16(ah[m], bh[n], acc[m][n], 0, 0, 0);
                acc[m][n] = __builtin_amdgcn_mfma_f32_16x16x32_bf16(ah[m], bl[n], acc[m][n], 0, 0, 0);
            }
        __syncthreads();
    }

    // fused attention coefficient partials (heads = 1)
    {
        float avs[4], avd[4];
#pragma unroll
        for (int n = 0; n < 4; ++n) {
            int col = wc + n * 16 + fr;
            avs[n] = aSrc[col]; avd[n] = aDst[col];
        }
#pragma unroll
        for (int m = 0; m < 4; ++m) {
            float ps[4], pd[4];
#pragma unroll
            for (int j = 0; j < 4; ++j) {
                ps[j] = acc[m][0][j] * avs[0] + acc[m][1][j] * avs[1]
                      + acc[m][2][j] * avs[2] + acc[m][3][j] * avs[3];
                pd[j] = acc[m][0][j] * avd[0] + acc[m][1][j] * avd[1]
                      + acc[m][2][j] * avd[2] + acc[m][3][j] * avd[3];
            }
#pragma unroll
            for (int off = 8; off; off >>= 1)
#pragma unroll
                for (int j = 0; j < 4; ++j) {
                    ps[j] += __shfl_xor(ps[j], off);
                    pd[j] += __shfl_xor(pd[j], off);
                }
            if (fr == 0) {
#pragma unroll
                for (int j = 0; j < 4; ++j) {
                    int grow = rowBase + wr + m * 16 + g * 4 + j;
                    if (grow < M) {
                        atomicAdd(asrcOut + grow, ps[j]);
                        atomicAdd(adstOut + grow, pd[j]);
                    }
                }
            }
        }
    }

    // transpose epilogue, bf16 C (N = 128)
    float* Cs = (float*)&smem[0][0][0];
    const int rl_w = (wr >> 6) * 16;
#pragma unroll
    for (int m = 0; m < 4; ++m) {
        __syncthreads();
#pragma unroll
        for (int n = 0; n < 4; ++n)
#pragma unroll
            for (int j = 0; j < 4; ++j)
                Cs[(rl_w + g * 4 + j) * 132 + wc + n * 16 + fr] = acc[m][n][j];
        __syncthreads();
        int rl = tid >> 3, c16 = (tid & 7) * 16;
        int grow = rowBase + (rl >> 4) * 64 + m * 16 + (rl & 15);
        if (grow < M) {
            unsigned short tmp[16];
#pragma unroll
            for (int i = 0; i < 16; ++i) tmp[i] = f2bf(Cs[rl * 132 + c16 + i]);
            *(uint4*)(Cb + (size_t)grow * 128 + c16)     = *(uint4*)&tmp[0];
            *(uint4*)(Cb + (size_t)grow * 128 + c16 + 8) = *(uint4*)&tmp[8];
        }
    }
}

// ---------------- SpMM layer 2 + fused softmax, bf16 x3 out ------------------
__global__ __launch_bounds__(256) void spmm2(
    const unsigned short* __restrict__ h2b, const float* __restrict__ asrc,
    const float* __restrict__ adst, const int* __restrict__ offs,
    const int* __restrict__ esrc,
    const float* __restrict__ b2, const float* __restrict__ gamma,
    const float* __restrict__ beta, const float* __restrict__ rm,
    const float* __restrict__ rv, unsigned short* __restrict__ x3b, int Nn)
{
    int d = (int)((blockIdx.x * blockDim.x + threadIdx.x) >> 6);
    int lane = threadIdx.x & 63;
    if (d >= Nn) return;
    int beg = offs[d], end = offs[d + 1];
    int deg = end - beg;
    float ad = adst[d];
    const int sub = lane >> 4;
    const int cgrp = lane & 15;
    const char* hb_c = (const char*)h2b + cgrp * 16;
    float acc[8] = {};

    if (deg <= 64) {
        int sj = 0; float ev = -1e30f;
        if (lane < deg) {
            sj = esrc[beg + lane];
            float e = asrc[sj] + ad; ev = e > 0.f ? e : NEG_SLOPE * e;
        }
        float m = ev;
        for (int off = 32; off; off >>= 1) m = fmaxf(m, __shfl_xor(m, off));
        float p = (lane < deg) ? expf(ev - m) : 0.f;
        float s = p;
        for (int off = 32; off; off >>= 1) s += __shfl_xor(s, off);
        float w = p * (1.f / s);
        gather1h(sj, w, deg, sub, hb_c, acc);
    } else {
        float m = -1e30f;
        for (int j = beg + lane; j < end; j += 64) {
            int s = esrc[j];
            float e = asrc[s] + ad; e = e > 0.f ? e : NEG_SLOPE * e;
            m = fmaxf(m, e);
        }
        for (int off = 32; off; off >>= 1) m = fmaxf(m, __shfl_xor(m, off));
        float sd = 0.f;
        for (int j = beg + lane; j < end; j += 64) {
            int s = esrc[j];
            float e = asrc[s] + ad; e = e > 0.f ? e : NEG_SLOPE * e;
            sd += expf(e - m);
        }
        for (int off = 32; off; off >>= 1) sd += __shfl_xor(sd, off);
        float rd = 1.f / sd;
        for (int base = beg; base < end; base += 64) {
            int nc = end - base; if (nc > 64) nc = 64;
            int sj = 0; float wj = 0.f;
            if (lane < nc) {
                sj = esrc[base + lane];
                float e = asrc[sj] + ad; e = e > 0.f ? e : NEG_SLOPE * e;
                wj = expf(e - m) * rd;
            }
            gather1h(sj, wj, nc, sub, hb_c, acc);
        }
    }
#pragma unroll
    for (int i = 0; i < 8; ++i) {
        acc[i] += __shfl_xor(acc[i], 32);
        acc[i] += __shfl_xor(acc[i], 16);
    }
    if (lane < 16) {
        int cl = cgrp * 8;
        unsigned short hh[8];
#pragma unroll
        for (int i = 0; i < 8; ++i) {
            int c = cl + i;
            float v = acc[i] + b2[c];
            v = gamma[c] * (v - rm[c]) * rsqrtf(rv[c] + EPSBN) + beta[c];
            hh[i] = f2bf(fmaxf(v, 0.f));
        }
        *(uint4*)(x3b + (size_t)d * 128 + cl) = *(uint4*)&hh[0];
    }
}

// ---------------- global max pool over bf16 x3: one block per graph ---------
__global__ __launch_bounds__(128) void pool_max_graph(
    const unsigned short* __restrict__ x3b, const int* __restrict__ bat,
    float* __restrict__ out, int Nn)
{
    int g = blockIdx.x;
    int c = threadIdx.x;
    int lo = 0, hi = Nn;
    while (lo < hi) { int mid = (lo + hi) >> 1; if (bat[mid] < g) lo = mid + 1; else hi = mid; }
    int beg = lo;
    hi = Nn;
    while (lo < hi) { int mid = (lo + hi) >> 1; if (bat[mid] < g + 1) lo = mid + 1; else hi = mid; }
    int end = lo;
    float acc = -1e30f;
    for (int n = beg; n < end; ++n)
        acc = fmaxf(acc, bfu2f((unsigned)x3b[(size_t)n * 128 + c]));
    out[(size_t)g * 128 + c] = acc;
}

// ---------------------------------------------------------------------------
extern "C" void kernel_launch(void* const* d_in, const int* in_sizes, int n_in,
                              void* d_out, int out_size, void* d_ws, size_t ws_size,
                              hipStream_t stream)
{
    const float* x   = (const float*)d_in[0];
    const int*   ei  = (const int*)d_in[1];
    const int*   bat = (const int*)d_in[2];
    const float* W1  = (const float*)d_in[3];
    const float* as1 = (const float*)d_in[4];
    const float* ad1 = (const float*)d_in[5];
    const float* b1  = (const float*)d_in[6];
    const float* g1  = (const float*)d_in[7];
    const float* be1 = (const float*)d_in[8];
    const float* rm1 = (const float*)d_in[9];
    const float* rv1 = (const float*)d_in[10];
    const float* W2  = (const float*)d_in[11];
    const float* as2 = (const float*)d_in[12];
    const float* ad2 = (const float*)d_in[13];
    const float* b2  = (const float*)d_in[14];
    const float* g2  = (const float*)d_in[15];
    const float* be2 = (const float*)d_in[16];
    const float* rm2 = (const float*)d_in[17];
    const float* rv2 = (const float*)d_in[18];
    float* out = (float*)d_out;

    const int Nn = in_sizes[0] / 128;
    const int E  = in_sizes[1] / 2;
    const int E2 = E + Nn;
    const int B  = out_size / 128;

    char* p = (char*)d_ws;
    size_t off = 0;
    auto alloc = [&](size_t bytes) -> void* {
        void* r = p + off;
        off = (off + bytes + 255) & ~(size_t)255;
        return r;
    };
    unsigned short* xh    = (unsigned short*)alloc((size_t)Nn * 128 * 2);
    unsigned short* w1th  = (unsigned short*)alloc(256 * 128 * 2);
    unsigned short* w1tl  = (unsigned short*)alloc(256 * 128 * 2);
    unsigned short* w2th  = (unsigned short*)alloc(128 * 256 * 2);
    unsigned short* w2tl  = (unsigned short*)alloc(128 * 256 * 2);
    unsigned short* xth   = (unsigned short*)alloc((size_t)Nn * 256 * 2);
    unsigned short* x2h   = (unsigned short*)alloc((size_t)Nn * 256 * 2);
    float*          vsd   = (float*)alloc(4 * 128 * 4);
    float*          asrc1 = (float*)alloc((size_t)Nn * 2 * 4);
    float*          adst1 = (float*)alloc((size_t)Nn * 2 * 4);
    float*          attnv = (float*)alloc((size_t)Nn * 2 * 4);   // asrc2, adst2
    float*          asrc2 = attnv;
    float*          adst2 = attnv + Nn;
    int*            counts= (int*)alloc((size_t)NREP * Nn * 4);  // replicas -> absolute offrep
    int*            erank = (int*)alloc((size_t)E2 * 4);
    int*            offs  = (int*)alloc((size_t)(Nn + 1) * 4);
    int*            bsum  = (int*)alloc(256 * 4);
    int*            esrc  = (int*)alloc((size_t)E2 * 4);
    // aliases (proven pattern): xth dead after gemm_bn_split -> x3b;
    // xh dead after spmm_x -> h2b target for layer-2 GEMM
    unsigned short* x3b   = xth;
    unsigned short* h2b   = xh;

    const int nb = (Nn + 255) / 256;
    const int nwB = (Nn + 3) / 4;
    const int countB = (E2 + 255) / 256;
    const int gmB = (Nn + 127) / 128;

    hipMemsetAsync(counts, 0, (size_t)NREP * Nn * 4, stream);
    hipMemsetAsync(attnv, 0, (size_t)Nn * 2 * 4, stream);

    // ---- prep: vsd, then fused {count_edges(8-rep) | split_x+attn | split_w}
    precompute_v<<<2, 256, 0, stream>>>(W1, as1, ad1, vsd);
    prep<<<countB + nwB + 256, 256, 0, stream>>>(
        x, vsd, W1, W2, ei, xh, asrc1, adst1,
        w1th, w1tl, w2th, w2tl, counts, erank, Nn, E, nwB, countB);

    // ---- CSR scan + fill (offrep fused: 1 random read per edge in fill)
    scan_block<<<nb, 256, 0, stream>>>(counts, offs, bsum, Nn);
    finalize_offsets<<<nb, 256, 0, stream>>>(bsum, offs, counts, Nn, E2);
    fill_edges<<<(E2 + 255) / 256, 256, 0, stream>>>(ei, E, Nn, counts, erank, esrc);

    // ---- layer 1: aggregate x (dual-head) then project + BN + ReLU
    spmm_x<<<nwB, 256, 0, stream>>>(xh, asrc1, adst1, offs, esrc, xth, Nn);
    gemm_bn_split<<<dim3(gmB, 2), 256, 0, stream>>>(
        xth, w1th, w1tl, b1, g1, be1, rm1, rv1, x2h, Nn);

    // ---- layer 2: GEMM (+attn coef) then SpMM (bf16 out)
    gemm_bf16_attn<<<gmB, 256, 0, stream>>>(
        x2h, w2th, w2tl, h2b, as2, ad2, asrc2, adst2, Nn);
    spmm2<<<nwB, 256, 0, stream>>>(h2b, asrc2, adst2, offs, esrc,
                                   b2, g2, be2, rm2, rv2, x3b, Nn);

    // ---- global max pool (bf16 in, f32 out)
    pool_max_graph<<<B, 128, 0, stream>>>(x3b, bat, out, Nn);
}